// Round 8
// baseline (224.470 us; speedup 1.0000x reference)
//
#include <hip/hip_runtime.h>

#define NN   4096
#define KNBR 8
#define DF   240
#define SUBW 8    // waves per kNN block (each covers 512 candidates)
#define QPB  64   // queries per kNN block (= lanes)

// Distance-only sorted-top-8 insert: pure med3/min chain, NO masks, NO bools.
__device__ __forceinline__ void insD(float v, float t[KNBR]) {
#pragma unroll
  for (int k = KNBR - 1; k >= 1; k--)
    t[k] = __builtin_amdgcn_fmed3f(t[k - 1], t[k], v);
  t[0] = fminf(t[0], v);
}

// (distance,index) sorted-top-8 insert — R5's proven low-VGPR formulation.
__device__ __forceinline__ void insertDI(float d2, int j, float bd[KNBR],
                                         int bi[KNBR]) {
#pragma unroll
  for (int k = KNBR - 1; k >= 1; k--) {
    bool mk  = d2 < bd[k];
    bool mk1 = d2 < bd[k - 1];
    bd[k] = mk ? (mk1 ? bd[k - 1] : d2) : bd[k];
    bi[k] = mk ? (mk1 ? bi[k - 1] : j) : bi[k];
  }
  bool m0 = d2 < bd[0];
  bd[0] = m0 ? d2 : bd[0];
  bi[0] = m0 ? j : bi[0];
}

__device__ __forceinline__ float bcast(float x, int l) {
  return __int_as_float(__builtin_amdgcn_readlane(__float_as_int(x), l));
}

// ---------------------------------------------------------------------------
// Kernel A: fuse weights.
//   WA = sA * (W2 @ L0)   (32x64)   ws[0..2048)
//   WB = sB * (W1 @ L1)   (64x32)   ws[2048..4096)
//   WC = sC * (W4 @ L1)   (16x32)   ws[4096..4608)
//   WD = sD * (W3 @ L2)   (32x16)   ws[4608..5120)
// ---------------------------------------------------------------------------
__global__ __launch_bounds__(256) void fuse_w(
    const float* __restrict__ W1, const float* __restrict__ W2,
    const float* __restrict__ W3, const float* __restrict__ W4,
    const float* __restrict__ L0, const float* __restrict__ L1,
    const float* __restrict__ L2, float* __restrict__ Wf) {
  const float sA = 0.012757759076995719f;  // sqrt(1/96)/8
  const float sB = 0.019764235376052370f;  // 1/sqrt(80*32)
  const float sC = 0.034232659844072875f;  // sqrt(3)/sqrt(80*32)
  const float sD = 0.098821176880261850f;  // sqrt(5/32)/4
  int idx = blockIdx.x * 256 + threadIdx.x;
  if (idx < 2048) {                       // WA: (32x64) = W2(32x64) @ L0(64x64)
    int u = idx >> 6, c = idx & 63;
    float a = 0.f;
#pragma unroll 8
    for (int m = 0; m < 64; m++) a += W2[u * 64 + m] * L0[m * 64 + c];
    Wf[idx] = sA * a;
  } else if (idx < 4096) {                // WB: (64x32) = W1(64x32) @ L1(32x32)
    int t = idx - 2048;
    int u = t >> 5, c = t & 31;
    float a = 0.f;
#pragma unroll 8
    for (int m = 0; m < 32; m++) a += W1[u * 32 + m] * L1[m * 32 + c];
    Wf[idx] = sB * a;
  } else if (idx < 4608) {                // WC: (16x32) = W4(16x32) @ L1(32x32)
    int t = idx - 4096;
    int u = t >> 5, c = t & 31;
    float a = 0.f;
#pragma unroll 8
    for (int m = 0; m < 32; m++) a += W4[u * 32 + m] * L1[m * 32 + c];
    Wf[idx] = sC * a;
  } else if (idx < 5120) {                // WD: (32x16) = W3(32x16) @ L2(16x16)
    int t = idx - 4608;
    int u = t >> 4, c = t & 15;
    float a = 0.f;
#pragma unroll 8
    for (int m = 0; m < 16; m++) a += W3[u * 16 + m] * L2[m * 16 + c];
    Wf[idx] = sD * a;
  }
}

// ---------------------------------------------------------------------------
// Kernel B: fused exact kNN (k=8). grid = B*64 = 256 blocks, 512 threads.
//   lane = query (64 per block), wave = 512-candidate range [sub*512, ..).
// Each wave stashes its 512 candidates' coords in 24 VGPRs (8 rounds x xyz),
// then both phases run load-free via v_readlane broadcast:
//   phase 1: distance-only top-8 (med3 chain, ~19 VALU/iter) -> LDS ->
//            wave 0 merges -> thr = exact per-query 8th-smallest d2.
//   phase 2: re-walk the stash; d2 <= thr (rare) -> insertDI -> LDS ->
//            wave 0 merges in ascending-sub (= ascending-j) order -> nbr.
// Stable-top_k exactness: thr is the exact 8th order statistic; collecting
// in ascending j with strict-< insertion keeps earliest-j ties, identical
// to jax.lax.top_k; capacity 8/sublist suffices (<=8 strictly below thr
// globally; ties at thr keep smallest j first).
// ---------------------------------------------------------------------------
__global__ __launch_bounds__(512) void knn_all(
    const float* __restrict__ coords, int* __restrict__ nbr) {
  __shared__ float pdist[SUBW][QPB][KNBR + 1];   // 18 KB (stride-9 pad)
  __shared__ float thrq[QPB];
  __shared__ float pd2[SUBW][QPB][KNBR + 1];     // 18 KB
  __shared__ int   pi2[SUBW][QPB][KNBR + 1];     // 18 KB
  const int blk = blockIdx.x;
  const int b = blk >> 6;              // 64 blocks per batch
  const int chunk = blk & 63;
  const int qi  = threadIdx.x & 63;    // lane = query
  const int sub = threadIdx.x >> 6;    // wave = candidate range
  const int iq  = chunk * 64 + qi;     // batch-local query id
  const float* cb = coords + (size_t)b * NN * 3;
  const float qx = cb[iq * 3 + 0], qy = cb[iq * 3 + 1], qz = cb[iq * 3 + 2];

  // Stash: lane i holds candidate (sub*512 + r*64 + i) for r = 0..7.
  const int j0 = sub * 512;
  float sxr[8], syr[8], szr[8];
#pragma unroll
  for (int r = 0; r < 8; r++) {
    int j = j0 + r * 64 + qi;
    sxr[r] = cb[j * 3 + 0];
    syr[r] = cb[j * 3 + 1];
    szr[r] = cb[j * 3 + 2];
  }

  // ---- phase 1: distance-only top-8 over this wave's 512 candidates ----
  float td[KNBR];
#pragma unroll
  for (int k = 0; k < KNBR; k++) td[k] = 3.0e38f;
#pragma unroll
  for (int r = 0; r < 8; r++) {
    int jbase = j0 + r * 64;
#pragma unroll 8
    for (int l = 0; l < 64; l++) {
      float cx = bcast(sxr[r], l);
      float cy = bcast(syr[r], l);
      float cz = bcast(szr[r], l);
      float dx = cx - qx, dy = cy - qy, dz = cz - qz;
      float d2 = dx * dx + dy * dy + dz * dz;
      d2 = (jbase + l == iq) ? 3.0e38f : d2;   // exclude self
      insD(d2, td);
    }
  }
#pragma unroll
  for (int k = 0; k < KNBR; k++) pdist[sub][qi][k] = td[k];
  __syncthreads();
  if (threadIdx.x < 64) {
    float md[KNBR];
#pragma unroll
    for (int k = 0; k < KNBR; k++) md[k] = 3.0e38f;
    for (int s = 0; s < SUBW; s++) {
#pragma unroll
      for (int k = 0; k < KNBR; k++) insD(pdist[s][qi][k], md);
    }
    thrq[qi] = md[KNBR - 1];
  }
  __syncthreads();
  const float tq = thrq[qi];

  // ---- phase 2: collect (d,j) for d2 <= thr, re-walking the stash ----
  float bd[KNBR];
  int bi[KNBR];
#pragma unroll
  for (int k = 0; k < KNBR; k++) { bd[k] = 3.0e38f; bi[k] = 0; }
#pragma unroll
  for (int r = 0; r < 8; r++) {
    int jbase = j0 + r * 64;
#pragma unroll 4
    for (int l = 0; l < 64; l++) {
      float cx = bcast(sxr[r], l);
      float cy = bcast(syr[r], l);
      float cz = bcast(szr[r], l);
      float dx = cx - qx, dy = cy - qy, dz = cz - qz;
      float d2 = dx * dx + dy * dy + dz * dz;
      int jj = jbase + l;
      d2 = (jj == iq) ? 3.0e38f : d2;
      if (d2 <= tq) insertDI(d2, jj, bd, bi);   // ~12% any-lane rate
    }
  }
#pragma unroll
  for (int k = 0; k < KNBR; k++) {
    pd2[sub][qi][k] = bd[k];
    pi2[sub][qi][k] = bi[k];
  }
  __syncthreads();
  if (threadIdx.x < 64) {
    float md[KNBR];
    int mi[KNBR];
#pragma unroll
    for (int k = 0; k < KNBR; k++) { md[k] = 3.0e38f; mi[k] = 0; }
    for (int s = 0; s < SUBW; s++) {
#pragma unroll
      for (int k = 0; k < KNBR; k++) {
        float vd = pd2[s][qi][k];
        if (vd < md[KNBR - 1]) insertDI(vd, pi2[s][qi][k], md, mi);
      }
    }
    int* nr = nbr + (size_t)(b * NN + iq) * KNBR;
#pragma unroll
    for (int k = 0; k < KNBR; k++) nr[k] = b * NN + mi[k];
  }
}

// ---------------------------------------------------------------------------
// Kernel C: gather neighbors, accumulate pre-weight moments, apply fused
// weights, write output. One wave (64 lanes) per node; 4 nodes per block.
//
// Moments per node (432 floats in LDS):
//   S1[32]    @ 0    : sum_e x1[u,:].ev
//   Z0[64][3] @ 32   : sum_e x0[u]*ev[k]
//   P [32][5] @ 224  : sum_e sum_i x1[u,i]*F[i][k]
//   Q [16][3] @ 384  : sum_e sum_a x2[u,a]*F[k][a]   (E2 = F^T)
// F(ev) 3x5, 11 nonzeros, S=1/sqrt(10), T=1/sqrt(30):
//   col0: (S*Y, S*X, 0)  col1: (S*Z, 0, S*X)  col2: (0, S*Z, S*Y)
//   col3: (S*X, -S*Y, 0) col4: (-T*X, -T*Y, 2T*Z)
// ---------------------------------------------------------------------------
__global__ __launch_bounds__(256) void msg_kernel(
    const float* __restrict__ feats, const float* __restrict__ coords,
    const int* __restrict__ nbr, const float* __restrict__ Wf,
    float* __restrict__ out) {
  __shared__ float fbuf[4][KNBR * DF];   // 4 x 1920 floats
  __shared__ float accb[4][432];
  __shared__ float sev[4][KNBR][3];
  __shared__ int snb[4][KNBR];

  const int w = threadIdx.x >> 6;   // wave within block -> node slot
  const int u = threadIdx.x & 63;   // lane
  const int node = blockIdx.x * 4 + w;

  if (u < KNBR) {
    int j = nbr[(size_t)node * KNBR + u];
    snb[w][u] = j;
    sev[w][u][0] = coords[j * 3 + 0] - coords[node * 3 + 0];
    sev[w][u][1] = coords[j * 3 + 1] - coords[node * 3 + 1];
    sev[w][u][2] = coords[j * 3 + 2] - coords[node * 3 + 2];
  }
  __syncthreads();

  // stage 8 neighbor feature rows (240 floats each) via float4
  {
    float4* fb4 = (float4*)fbuf[w];
    const float4* gf4 = (const float4*)feats;
#pragma unroll
    for (int it = 0; it < 8; it++) {
      int idx = u + it * 64;
      if (idx < KNBR * (DF / 4)) {
        int e = idx / 60;
        int r = idx - e * 60;
        fb4[idx] = gf4[(size_t)snb[w][e] * 60 + r];
      }
    }
  }
  __syncthreads();

  const float S_ = 0.31622776601683794f;  // 1/sqrt(10)
  const float T_ = 0.18257418583505536f;  // 1/sqrt(30)

  float z0x = 0.f, z0y = 0.f, z0z = 0.f;
  float s1 = 0.f, p0 = 0.f, p1 = 0.f, p2 = 0.f, p3 = 0.f, p4 = 0.f;
  float q0 = 0.f, q1 = 0.f, q2 = 0.f;
  const float* fw = fbuf[w];

#pragma unroll
  for (int e = 0; e < KNBR; e++) {
    float X = sev[w][e][0], Y = sev[w][e][1], Z = sev[w][e][2];
    float sxv = S_ * X, syv = S_ * Y, szv = S_ * Z;
    float txv = T_ * X, tyv = T_ * Y, t2z = 2.f * T_ * Z;
    const float* fr = fw + e * DF;
    float x0v = fr[u];
    z0x += x0v * X;
    z0y += x0v * Y;
    z0z += x0v * Z;
    if (u < 32) {
      float a0 = fr[64 + 3 * u], a1 = fr[65 + 3 * u], a2 = fr[66 + 3 * u];
      s1 += a0 * X + a1 * Y + a2 * Z;
      p0 += a0 * syv + a1 * sxv;
      p1 += a0 * szv + a2 * sxv;
      p2 += a1 * szv + a2 * syv;
      p3 += a0 * sxv - a1 * syv;
      p4 += a2 * t2z - a0 * txv - a1 * tyv;
      if (u < 16) {
        float b0 = fr[160 + 5 * u], b1 = fr[161 + 5 * u], b2 = fr[162 + 5 * u];
        float b3 = fr[163 + 5 * u], b4 = fr[164 + 5 * u];
        q0 += b0 * syv + b1 * szv + b3 * sxv - b4 * txv;
        q1 += b0 * sxv + b2 * szv - b3 * syv - b4 * tyv;
        q2 += b1 * sxv + b2 * syv + b4 * t2z;
      }
    }
  }

  float* A = accb[w];
  A[32 + 3 * u + 0] = z0x;
  A[32 + 3 * u + 1] = z0y;
  A[32 + 3 * u + 2] = z0z;
  if (u < 32) {
    A[u] = s1;
    float* pp = A + 224 + 5 * u;
    pp[0] = p0; pp[1] = p1; pp[2] = p2; pp[3] = p3; pp[4] = p4;
  }
  if (u < 16) {
    float* qq = A + 384 + 3 * u;
    qq[0] = q0; qq[1] = q1; qq[2] = q2;
  }
  __syncthreads();

  const float* WA = Wf;          // 32x64
  const float* WB = Wf + 2048;   // 64x32
  const float* WC = Wf + 4096;   // 16x32
  const float* WD = Wf + 4608;   // 32x16
  float* orow = out + (size_t)node * DF;

  // y0[u] = sum_m S1[m] * WA[m][u]
  {
    float a = 0.f;
#pragma unroll
    for (int m = 0; m < 32; m++) a += A[m] * WA[m * 64 + u];
    orow[u] = a;
  }
  // y1 flat [w1*3+k], 96 outputs (two passes over 64 lanes)
#pragma unroll
  for (int m0 = 0; m0 < 96; m0 += 64) {
    int m = m0 + u;
    if (m < 96) {
      int w1 = m / 3, k = m - w1 * 3;
      float a = 0.f;
#pragma unroll
      for (int t = 0; t < 64; t++) a += A[32 + 3 * t + k] * WB[t * 32 + w1];
#pragma unroll
      for (int t = 0; t < 16; t++) a += A[384 + 3 * t + k] * WC[t * 32 + w1];
      orow[64 + m] = a;
    }
  }
  // y2 flat [w2*5+k], 80 outputs (two passes over 64 lanes)
#pragma unroll
  for (int m0 = 0; m0 < 80; m0 += 64) {
    int m = m0 + u;
    if (m < 80) {
      int w2 = m / 5, k = m - w2 * 5;
      float a = 0.f;
#pragma unroll
      for (int t = 0; t < 32; t++) a += A[224 + 5 * t + k] * WD[t * 16 + w2];
      orow[160 + m] = a;
    }
  }
}

// ---------------------------------------------------------------------------
extern "C" void kernel_launch(void* const* d_in, const int* in_sizes, int n_in,
                              void* d_out, int out_size, void* d_ws,
                              size_t ws_size, hipStream_t stream) {
  const float* feats  = (const float*)d_in[0];
  const float* coords = (const float*)d_in[1];
  const float* W1 = (const float*)d_in[2];
  const float* W2 = (const float*)d_in[3];
  const float* W3 = (const float*)d_in[4];
  const float* W4 = (const float*)d_in[5];
  const float* L0 = (const float*)d_in[6];
  const float* L1 = (const float*)d_in[7];
  const float* L2 = (const float*)d_in[8];
  float* out = (float*)d_out;

  // workspace (floats): Wf[5120] | nbr[131072 ints]
  float* Wf  = (float*)d_ws;
  int*   nbr = (int*)((float*)d_ws + 5120);

  fuse_w<<<20, 256, 0, stream>>>(W1, W2, W3, W4, L0, L1, L2, Wf);
  knn_all<<<256, 512, 0, stream>>>(coords, nbr);
  msg_kernel<<<4096, 256, 0, stream>>>(feats, coords, nbr, Wf, out);
}

// Round 9
// 220.219 us; speedup vs baseline: 1.0193x; 1.0193x over previous
//
#include <hip/hip_runtime.h>

#define NN   4096
#define KNBR 8
#define DF   240
#define SUBW 16   // waves per kNN block (each covers 256 candidates)
#define QPB  64   // queries per kNN block (= lanes)
#define RNDS 4    // stash rounds per wave: 4*64 = 256 candidates

// Distance-only sorted-top-8 insert: pure med3/min chain, NO masks, NO bools.
__device__ __forceinline__ void insD(float v, float t[KNBR]) {
#pragma unroll
  for (int k = KNBR - 1; k >= 1; k--)
    t[k] = __builtin_amdgcn_fmed3f(t[k - 1], t[k], v);
  t[0] = fminf(t[0], v);
}

// (distance,index) sorted-top-8 insert — R5's proven low-VGPR formulation.
__device__ __forceinline__ void insertDI(float d2, int j, float bd[KNBR],
                                         int bi[KNBR]) {
#pragma unroll
  for (int k = KNBR - 1; k >= 1; k--) {
    bool mk  = d2 < bd[k];
    bool mk1 = d2 < bd[k - 1];
    bd[k] = mk ? (mk1 ? bd[k - 1] : d2) : bd[k];
    bi[k] = mk ? (mk1 ? bi[k - 1] : j) : bi[k];
  }
  bool m0 = d2 < bd[0];
  bd[0] = m0 ? d2 : bd[0];
  bi[0] = m0 ? j : bi[0];
}

__device__ __forceinline__ float bcast(float x, int l) {
  return __int_as_float(__builtin_amdgcn_readlane(__float_as_int(x), l));
}

// ---------------------------------------------------------------------------
// Kernel A: fuse weights.
//   WA = sA * (W2 @ L0)   (32x64)   ws[0..2048)
//   WB = sB * (W1 @ L1)   (64x32)   ws[2048..4096)
//   WC = sC * (W4 @ L1)   (16x32)   ws[4096..4608)
//   WD = sD * (W3 @ L2)   (32x16)   ws[4608..5120)
// ---------------------------------------------------------------------------
__global__ __launch_bounds__(256) void fuse_w(
    const float* __restrict__ W1, const float* __restrict__ W2,
    const float* __restrict__ W3, const float* __restrict__ W4,
    const float* __restrict__ L0, const float* __restrict__ L1,
    const float* __restrict__ L2, float* __restrict__ Wf) {
  const float sA = 0.012757759076995719f;  // sqrt(1/96)/8
  const float sB = 0.019764235376052370f;  // 1/sqrt(80*32)
  const float sC = 0.034232659844072875f;  // sqrt(3)/sqrt(80*32)
  const float sD = 0.098821176880261850f;  // sqrt(5/32)/4
  int idx = blockIdx.x * 256 + threadIdx.x;
  if (idx < 2048) {                       // WA: (32x64) = W2(32x64) @ L0(64x64)
    int u = idx >> 6, c = idx & 63;
    float a = 0.f;
#pragma unroll 8
    for (int m = 0; m < 64; m++) a += W2[u * 64 + m] * L0[m * 64 + c];
    Wf[idx] = sA * a;
  } else if (idx < 4096) {                // WB: (64x32) = W1(64x32) @ L1(32x32)
    int t = idx - 2048;
    int u = t >> 5, c = t & 31;
    float a = 0.f;
#pragma unroll 8
    for (int m = 0; m < 32; m++) a += W1[u * 32 + m] * L1[m * 32 + c];
    Wf[idx] = sB * a;
  } else if (idx < 4608) {                // WC: (16x32) = W4(16x32) @ L1(32x32)
    int t = idx - 4096;
    int u = t >> 5, c = t & 31;
    float a = 0.f;
#pragma unroll 8
    for (int m = 0; m < 32; m++) a += W4[u * 32 + m] * L1[m * 32 + c];
    Wf[idx] = sC * a;
  } else if (idx < 5120) {                // WD: (32x16) = W3(32x16) @ L2(16x16)
    int t = idx - 4608;
    int u = t >> 4, c = t & 15;
    float a = 0.f;
#pragma unroll 8
    for (int m = 0; m < 16; m++) a += W3[u * 16 + m] * L2[m * 16 + c];
    Wf[idx] = sD * a;
  }
}

// ---------------------------------------------------------------------------
// Kernel B: fused exact kNN (k=8). grid = B*64 = 256 blocks, 1024 threads
// (16 waves -> 4 waves/SIMD; R8 had 8 waves -> 2/SIMD, VALUBusy 66%).
//   lane = query (64 per block), wave = 256-candidate range [sub*256, ..).
// Each wave stashes its 256 candidates' coords in 12 VGPRs (4 rounds x xyz);
// both phases run load-free via v_readlane broadcast:
//   phase 1: distance-only top-8 (med3 chain) -> LDS -> wave 0 merges 16
//            sublists -> thr = exact per-query 8th-smallest d2.
//   phase 2: re-walk the stash; d2 <= thr (rare) -> insertDI -> LDS ->
//            wave 0 merges in ascending-sub (= ascending-j) order -> nbr.
// LDS: phase-2 distance sublists ALIAS the phase-1 sublists (dead after thr;
// barrier-separated); indices stored as ushort (j < 4096). 55.5 KB total.
// Stable-top_k exactness: thr is the exact 8th order statistic; collecting
// in ascending j with strict-< insertion keeps earliest-j ties, identical
// to jax.lax.top_k.
// ---------------------------------------------------------------------------
__global__ __launch_bounds__(1024) void knn_all(
    const float* __restrict__ coords, int* __restrict__ nbr) {
  __shared__ float pdist[SUBW][QPB][KNBR + 1];        // 36.9 KB; reused as pd2
  __shared__ unsigned short pi2s[SUBW][QPB][KNBR + 1];// 18.4 KB
  __shared__ float thrq[QPB];
  const int blk = blockIdx.x;
  const int b = blk >> 6;              // 64 blocks per batch
  const int chunk = blk & 63;
  const int qi  = threadIdx.x & 63;    // lane = query
  const int sub = threadIdx.x >> 6;    // wave = candidate range
  const int iq  = chunk * 64 + qi;     // batch-local query id
  const float* cb = coords + (size_t)b * NN * 3;
  const float qx = cb[iq * 3 + 0], qy = cb[iq * 3 + 1], qz = cb[iq * 3 + 2];

  // Stash: lane i holds candidate (sub*256 + r*64 + i) for r = 0..3.
  const int j0 = sub * (RNDS * 64);
  float sxr[RNDS], syr[RNDS], szr[RNDS];
#pragma unroll
  for (int r = 0; r < RNDS; r++) {
    int j = j0 + r * 64 + qi;
    sxr[r] = cb[j * 3 + 0];
    syr[r] = cb[j * 3 + 1];
    szr[r] = cb[j * 3 + 2];
  }

  // ---- phase 1: distance-only top-8 over this wave's 256 candidates ----
  float td[KNBR];
#pragma unroll
  for (int k = 0; k < KNBR; k++) td[k] = 3.0e38f;
#pragma unroll
  for (int r = 0; r < RNDS; r++) {
    int jbase = j0 + r * 64;
#pragma unroll 8
    for (int l = 0; l < 64; l++) {
      float cx = bcast(sxr[r], l);
      float cy = bcast(syr[r], l);
      float cz = bcast(szr[r], l);
      float dx = cx - qx, dy = cy - qy, dz = cz - qz;
      float d2 = dx * dx + dy * dy + dz * dz;
      d2 = (jbase + l == iq) ? 3.0e38f : d2;   // exclude self
      insD(d2, td);
    }
  }
#pragma unroll
  for (int k = 0; k < KNBR; k++) pdist[sub][qi][k] = td[k];
  __syncthreads();
  if (threadIdx.x < 64) {
    float md[KNBR];
#pragma unroll
    for (int k = 0; k < KNBR; k++) md[k] = 3.0e38f;
    for (int s = 0; s < SUBW; s++) {
#pragma unroll
      for (int k = 0; k < KNBR; k++) insD(pdist[s][qi][k], md);
    }
    thrq[qi] = md[KNBR - 1];
  }
  __syncthreads();
  const float tq = thrq[qi];

  // ---- phase 2: collect (d,j) for d2 <= thr, re-walking the stash ----
  // (pdist now dead -> reused as the phase-2 distance sublists)
  float bd[KNBR];
  int bi[KNBR];
#pragma unroll
  for (int k = 0; k < KNBR; k++) { bd[k] = 3.0e38f; bi[k] = 0; }
#pragma unroll
  for (int r = 0; r < RNDS; r++) {
    int jbase = j0 + r * 64;
#pragma unroll 4
    for (int l = 0; l < 64; l++) {
      float cx = bcast(sxr[r], l);
      float cy = bcast(syr[r], l);
      float cz = bcast(szr[r], l);
      float dx = cx - qx, dy = cy - qy, dz = cz - qz;
      float d2 = dx * dx + dy * dy + dz * dz;
      int jj = jbase + l;
      d2 = (jj == iq) ? 3.0e38f : d2;
      if (d2 <= tq) insertDI(d2, jj, bd, bi);   // ~12% any-lane rate
    }
  }
#pragma unroll
  for (int k = 0; k < KNBR; k++) {
    pdist[sub][qi][k] = bd[k];
    pi2s[sub][qi][k] = (unsigned short)bi[k];
  }
  __syncthreads();
  if (threadIdx.x < 64) {
    float md[KNBR];
    int mi[KNBR];
#pragma unroll
    for (int k = 0; k < KNBR; k++) { md[k] = 3.0e38f; mi[k] = 0; }
    for (int s = 0; s < SUBW; s++) {
#pragma unroll
      for (int k = 0; k < KNBR; k++) {
        float vd = pdist[s][qi][k];
        if (vd < md[KNBR - 1]) insertDI(vd, (int)pi2s[s][qi][k], md, mi);
      }
    }
    int* nr = nbr + (size_t)(b * NN + iq) * KNBR;
#pragma unroll
    for (int k = 0; k < KNBR; k++) nr[k] = b * NN + mi[k];
  }
}

// ---------------------------------------------------------------------------
// Kernel C: gather neighbors, accumulate pre-weight moments, apply fused
// weights, write output. One wave (64 lanes) per node; 4 nodes per block.
//
// Moments per node (432 floats in LDS):
//   S1[32]    @ 0    : sum_e x1[u,:].ev
//   Z0[64][3] @ 32   : sum_e x0[u]*ev[k]
//   P [32][5] @ 224  : sum_e sum_i x1[u,i]*F[i][k]
//   Q [16][3] @ 384  : sum_e sum_a x2[u,a]*F[k][a]   (E2 = F^T)
// F(ev) 3x5, 11 nonzeros, S=1/sqrt(10), T=1/sqrt(30):
//   col0: (S*Y, S*X, 0)  col1: (S*Z, 0, S*X)  col2: (0, S*Z, S*Y)
//   col3: (S*X, -S*Y, 0) col4: (-T*X, -T*Y, 2T*Z)
// ---------------------------------------------------------------------------
__global__ __launch_bounds__(256) void msg_kernel(
    const float* __restrict__ feats, const float* __restrict__ coords,
    const int* __restrict__ nbr, const float* __restrict__ Wf,
    float* __restrict__ out) {
  __shared__ float fbuf[4][KNBR * DF];   // 4 x 1920 floats
  __shared__ float accb[4][432];
  __shared__ float sev[4][KNBR][3];
  __shared__ int snb[4][KNBR];

  const int w = threadIdx.x >> 6;   // wave within block -> node slot
  const int u = threadIdx.x & 63;   // lane
  const int node = blockIdx.x * 4 + w;

  if (u < KNBR) {
    int j = nbr[(size_t)node * KNBR + u];
    snb[w][u] = j;
    sev[w][u][0] = coords[j * 3 + 0] - coords[node * 3 + 0];
    sev[w][u][1] = coords[j * 3 + 1] - coords[node * 3 + 1];
    sev[w][u][2] = coords[j * 3 + 2] - coords[node * 3 + 2];
  }
  __syncthreads();

  // stage 8 neighbor feature rows (240 floats each) via float4
  {
    float4* fb4 = (float4*)fbuf[w];
    const float4* gf4 = (const float4*)feats;
#pragma unroll
    for (int it = 0; it < 8; it++) {
      int idx = u + it * 64;
      if (idx < KNBR * (DF / 4)) {
        int e = idx / 60;
        int r = idx - e * 60;
        fb4[idx] = gf4[(size_t)snb[w][e] * 60 + r];
      }
    }
  }
  __syncthreads();

  const float S_ = 0.31622776601683794f;  // 1/sqrt(10)
  const float T_ = 0.18257418583505536f;  // 1/sqrt(30)

  float z0x = 0.f, z0y = 0.f, z0z = 0.f;
  float s1 = 0.f, p0 = 0.f, p1 = 0.f, p2 = 0.f, p3 = 0.f, p4 = 0.f;
  float q0 = 0.f, q1 = 0.f, q2 = 0.f;
  const float* fw = fbuf[w];

#pragma unroll
  for (int e = 0; e < KNBR; e++) {
    float X = sev[w][e][0], Y = sev[w][e][1], Z = sev[w][e][2];
    float sxv = S_ * X, syv = S_ * Y, szv = S_ * Z;
    float txv = T_ * X, tyv = T_ * Y, t2z = 2.f * T_ * Z;
    const float* fr = fw + e * DF;
    float x0v = fr[u];
    z0x += x0v * X;
    z0y += x0v * Y;
    z0z += x0v * Z;
    if (u < 32) {
      float a0 = fr[64 + 3 * u], a1 = fr[65 + 3 * u], a2 = fr[66 + 3 * u];
      s1 += a0 * X + a1 * Y + a2 * Z;
      p0 += a0 * syv + a1 * sxv;
      p1 += a0 * szv + a2 * sxv;
      p2 += a1 * szv + a2 * syv;
      p3 += a0 * sxv - a1 * syv;
      p4 += a2 * t2z - a0 * txv - a1 * tyv;
      if (u < 16) {
        float b0 = fr[160 + 5 * u], b1 = fr[161 + 5 * u], b2 = fr[162 + 5 * u];
        float b3 = fr[163 + 5 * u], b4 = fr[164 + 5 * u];
        q0 += b0 * syv + b1 * szv + b3 * sxv - b4 * txv;
        q1 += b0 * sxv + b2 * szv - b3 * syv - b4 * tyv;
        q2 += b1 * sxv + b2 * syv + b4 * t2z;
      }
    }
  }

  float* A = accb[w];
  A[32 + 3 * u + 0] = z0x;
  A[32 + 3 * u + 1] = z0y;
  A[32 + 3 * u + 2] = z0z;
  if (u < 32) {
    A[u] = s1;
    float* pp = A + 224 + 5 * u;
    pp[0] = p0; pp[1] = p1; pp[2] = p2; pp[3] = p3; pp[4] = p4;
  }
  if (u < 16) {
    float* qq = A + 384 + 3 * u;
    qq[0] = q0; qq[1] = q1; qq[2] = q2;
  }
  __syncthreads();

  const float* WA = Wf;          // 32x64
  const float* WB = Wf + 2048;   // 64x32
  const float* WC = Wf + 4096;   // 16x32
  const float* WD = Wf + 4608;   // 32x16
  float* orow = out + (size_t)node * DF;

  // y0[u] = sum_m S1[m] * WA[m][u]
  {
    float a = 0.f;
#pragma unroll
    for (int m = 0; m < 32; m++) a += A[m] * WA[m * 64 + u];
    orow[u] = a;
  }
  // y1 flat [w1*3+k], 96 outputs (two passes over 64 lanes)
#pragma unroll
  for (int m0 = 0; m0 < 96; m0 += 64) {
    int m = m0 + u;
    if (m < 96) {
      int w1 = m / 3, k = m - w1 * 3;
      float a = 0.f;
#pragma unroll
      for (int t = 0; t < 64; t++) a += A[32 + 3 * t + k] * WB[t * 32 + w1];
#pragma unroll
      for (int t = 0; t < 16; t++) a += A[384 + 3 * t + k] * WC[t * 32 + w1];
      orow[64 + m] = a;
    }
  }
  // y2 flat [w2*5+k], 80 outputs (two passes over 64 lanes)
#pragma unroll
  for (int m0 = 0; m0 < 80; m0 += 64) {
    int m = m0 + u;
    if (m < 80) {
      int w2 = m / 5, k = m - w2 * 5;
      float a = 0.f;
#pragma unroll
      for (int t = 0; t < 32; t++) a += A[224 + 5 * t + k] * WD[t * 16 + w2];
      orow[160 + m] = a;
    }
  }
}

// ---------------------------------------------------------------------------
extern "C" void kernel_launch(void* const* d_in, const int* in_sizes, int n_in,
                              void* d_out, int out_size, void* d_ws,
                              size_t ws_size, hipStream_t stream) {
  const float* feats  = (const float*)d_in[0];
  const float* coords = (const float*)d_in[1];
  const float* W1 = (const float*)d_in[2];
  const float* W2 = (const float*)d_in[3];
  const float* W3 = (const float*)d_in[4];
  const float* W4 = (const float*)d_in[5];
  const float* L0 = (const float*)d_in[6];
  const float* L1 = (const float*)d_in[7];
  const float* L2 = (const float*)d_in[8];
  float* out = (float*)d_out;

  // workspace (floats): Wf[5120] | nbr[131072 ints]
  float* Wf  = (float*)d_ws;
  int*   nbr = (int*)((float*)d_ws + 5120);

  fuse_w<<<20, 256, 0, stream>>>(W1, W2, W3, W4, L0, L1, L2, Wf);
  knn_all<<<256, 1024, 0, stream>>>(coords, nbr);
  msg_kernel<<<4096, 256, 0, stream>>>(feats, coords, nbr, Wf, out);
}